// Round 6
// baseline (747.885 us; speedup 1.0000x reference)
//
#include <hip/hip_runtime.h>
#include <math.h>

#define NN 512
#define HH 256
#define BB 32
#define NE 130816

typedef unsigned short ushort_t;
typedef unsigned int u32;
using short8  = __attribute__((ext_vector_type(8))) short;
using floatx4 = __attribute__((ext_vector_type(4))) float;

// ---------- bf16 helpers (RNE) ----------
__device__ inline unsigned short f2bf(float f) {
    unsigned int u = __float_as_uint(f);
    unsigned int r = (u + 0x7fffu + ((u >> 16) & 1u)) >> 16;
    return (unsigned short)r;
}
__device__ inline float bf2f(unsigned short x) {
    return __uint_as_float(((unsigned int)x) << 16);
}

// ---------- reduction helpers ----------
__device__ inline float wave_reduce_sum(float v) {
#pragma unroll
    for (int o = 32; o > 0; o >>= 1) v += __shfl_xor(v, o, 64);
    return v;
}
__device__ inline float block_reduce_sum256(float v, float* red) {
    v = wave_reduce_sum(v);
    int w = threadIdx.x >> 6;
    if ((threadIdx.x & 63) == 0) red[w] = v;
    __syncthreads();
    v = red[0] + red[1] + red[2] + red[3];
    __syncthreads();
    return v;
}

// ---------- 1) schedule init + out zero ----------
__global__ void init_kernel(float* __restrict__ sched, float* __restrict__ out) {
    __shared__ float alpha_s[100];
    int tid = threadIdx.x;
    if (tid < 100) {
        const double PI_H = 3.14159265358979323846 * 0.5;
        double f1 = (((double)tid / 100.0) + 0.008) / 1.008 * PI_H;
        double f2 = (((double)(tid + 1) / 100.0) + 0.008) / 1.008 * PI_H;
        double c1 = cos(f1), c2 = cos(f2);
        double beta = 1.0 - (c2 * c2) / (c1 * c1);
        if (beta > 0.999) beta = 0.999;
        alpha_s[tid] = 1.0f - (float)beta;
    }
    __syncthreads();
    if (tid == 0) {
        out[0] = 0.0f;
        float cum = 1.0f;
        for (int k = 0; k < 100; k++) {
            cum *= alpha_s[k];
            sched[k]       = sqrtf(cum);
            sched[100 + k] = sqrtf(1.0f - cum);
        }
    }
}

// ---------- 2a) emb = silu(tf@W1+b1)@W2 + b2 ; grid (32 b, 4 colblk) ----------
__global__ __launch_bounds__(256) void temb1_kernel(
    const float* __restrict__ te_W1, const float* __restrict__ te_b1,
    const float* __restrict__ te_W2, const float* __restrict__ te_b2,
    const int* __restrict__ t, float* __restrict__ emb_out) {
    const int b = blockIdx.x, cb = blockIdx.y * 64, tid = threadIdx.x;
    __shared__ float hid[HH];
    __shared__ float part[4][64];
    float tf = (float)t[b] / 100.0f;
    float z = tf * te_W1[tid] + te_b1[tid];
    hid[tid] = z / (1.0f + expf(-z));
    __syncthreads();
    const int col = tid & 63, kc = tid >> 6;
    float a = 0.0f;
#pragma unroll 8
    for (int k0 = 0; k0 < 64; k0++) {
        int k = kc * 64 + k0;
        a = fmaf(hid[k], te_W2[k * HH + cb + col], a);
    }
    part[kc][col] = a;
    __syncthreads();
    if (kc == 0) {
        float o = part[0][col] + part[1][col] + part[2][col] + part[3][col] + te_b2[cb + col];
        emb_out[b * HH + cb + col] = o;
    }
}

// ---------- 2b) tbias[l,b,:] = emb[b]@tp_W[l] + tp_b[l] ; grid (32 b, 16) ----------
__global__ __launch_bounds__(256) void temb2_kernel(
    const float* __restrict__ emb, const float* __restrict__ tp_W,
    const float* __restrict__ tp_b, float* __restrict__ tbias_out) {
    const int b = blockIdx.x;
    const int l = blockIdx.y >> 2, cb = (blockIdx.y & 3) * 64;
    const int tid = threadIdx.x;
    __shared__ float es[HH];
    __shared__ float part[4][64];
    es[tid] = emb[b * HH + tid];
    __syncthreads();
    const int col = tid & 63, kc = tid >> 6;
    const float* W = tp_W + l * HH * HH;
    float a = 0.0f;
#pragma unroll 8
    for (int k0 = 0; k0 < 64; k0++) {
        int k = kc * 64 + k0;
        a = fmaf(es[k], W[k * HH + cb + col], a);
    }
    part[kc][col] = a;
    __syncthreads();
    if (kc == 0) {
        float o = part[0][col] + part[1][col] + part[2][col] + part[3][col]
                + tp_b[l * HH + cb + col];
        tbias_out[l * (BB * HH) + b * HH + cb + col] = o;
    }
}

// ---------- 3) adj_t (bf16) + inverse row abs-sum; wave-per-row, no barriers ----------
__global__ __launch_bounds__(256) void adj_kernel(
    const float* __restrict__ adj0, const float* __restrict__ noise,
    const int* __restrict__ t, const float* __restrict__ sched,
    ushort_t* __restrict__ adjt_bf, float* __restrict__ invrs) {
    const int row = blockIdx.x * 4 + (threadIdx.x >> 6);
    const int lane = threadIdx.x & 63;
    const int b = row >> 9;
    const int ts = t[b];
    const float sab = sched[ts], som = sched[100 + ts];
    const size_t base = (size_t)row * NN + lane * 8;
    float4 a0 = *(const float4*)(adj0 + base);
    float4 a1 = *(const float4*)(adj0 + base + 4);
    float4 q0 = *(const float4*)(noise + base);
    float4 q1 = *(const float4*)(noise + base + 4);
    float v0 = fmaf(sab, a0.x, som * q0.x), v1 = fmaf(sab, a0.y, som * q0.y);
    float v2 = fmaf(sab, a0.z, som * q0.z), v3 = fmaf(sab, a0.w, som * q0.w);
    float v4 = fmaf(sab, a1.x, som * q1.x), v5 = fmaf(sab, a1.y, som * q1.y);
    float v6 = fmaf(sab, a1.z, som * q1.z), v7 = fmaf(sab, a1.w, som * q1.w);
    uint4 pk;
    pk.x = (u32)f2bf(v0) | ((u32)f2bf(v1) << 16);
    pk.y = (u32)f2bf(v2) | ((u32)f2bf(v3) << 16);
    pk.z = (u32)f2bf(v4) | ((u32)f2bf(v5) << 16);
    pk.w = (u32)f2bf(v6) | ((u32)f2bf(v7) << 16);
    *(uint4*)(adjt_bf + base) = pk;
    float s = fabsf(v0) + fabsf(v1) + fabsf(v2) + fabsf(v3)
            + fabsf(v4) + fabsf(v5) + fabsf(v6) + fabsf(v7);
    s = wave_reduce_sum(s);
    if (lane == 0) invrs[row] = 1.0f / (s + 1.0f);
}

// ---------- 4) weight convert ----------
// z=0: ip_W (512x256) -> ipWT (256x512 T); z=1..4: msg_W -> msgWbf (row-major);
// z=5..8: upd_W (512x256) -> updWT (256x512 T)
__global__ __launch_bounds__(256) void wcvt_kernel(
    const float* __restrict__ ip_W, const float* __restrict__ msg_W,
    const float* __restrict__ upd_W,
    ushort_t* __restrict__ ipWT, ushort_t* __restrict__ msgWbf,
    ushort_t* __restrict__ updWT) {
    const int z = blockIdx.z;
    const int r0 = blockIdx.y * 32, c0 = blockIdx.x * 32;
    const int tr = threadIdx.x >> 5, tc = threadIdx.x & 31;
    if (z >= 1 && z <= 4) {
        const float* src = msg_W + (z - 1) * 65536;
        ushort_t* dst = msgWbf + (z - 1) * 65536;
        if (r0 >= 256) return;
#pragma unroll
        for (int s = 0; s < 32; s += 8)
            dst[(size_t)(r0 + tr + s) * 256 + c0 + tc] =
                f2bf(src[(size_t)(r0 + tr + s) * 256 + c0 + tc]);
        return;
    }
    const float* src; ushort_t* dst; int R;
    if (z == 0) { src = ip_W;                     dst = ipWT;                     R = 512; }
    else        { src = upd_W + (z - 5) * 131072; dst = updWT + (z - 5) * 131072; R = 512; }
    __shared__ float T[32][33];
#pragma unroll
    for (int s = 0; s < 32; s += 8)
        T[tr + s][tc] = src[(size_t)(r0 + tr + s) * 256 + c0 + tc];
    __syncthreads();
#pragma unroll
    for (int s = 0; s < 32; s += 8)
        dst[(size_t)(c0 + tr + s) * R + r0 + tc] = f2bf(T[tc][tr + s]);
}

// ---------- 5) bfv[l] = msg_b[l] @ Wu2[l]  (fp32) ----------
__global__ __launch_bounds__(256) void bfv_kernel(
    const float* __restrict__ msg_b, const float* __restrict__ upd_W,
    float* __restrict__ bfv) {
    const int l = blockIdx.x, n = threadIdx.x;
    float a = 0.0f;
#pragma unroll 8
    for (int j = 0; j < 256; j++)
        a = fmaf(msg_b[l * 256 + j], upd_W[(size_t)l * 131072 + (size_t)(256 + j) * 256 + n], a);
    bfv[l * 256 + n] = a;
}

// ---------- 6) LDS-free bf16 MFMA GEMM: tile 128x64, no barriers in K-loop ----------
// A-frags and B-frags loaded per-lane 16B directly from global (L2-served reuse).
// C(M x Ntot) = A(MxK) @ B; BT[n][k] transposed. Region split at nsplit:
//  n0 < nsplit -> BT/ldbt, row-major epilogue (Cf/Cb);
//  n0 >= nsplit -> BT2/ldbt2 (+bias2), per-batch transposed store to CbT (one barrier).
// bstride: per-512-row-batch B stride. z: batched weights (WfT prep).
template<int K>
__global__ __launch_bounds__(256) void gemm_nolds(
    int nsplit,
    const ushort_t* __restrict__ A, int lda, long long aStrideZ,
    const ushort_t* __restrict__ BT, int ldbt,
    const ushort_t* __restrict__ BT2, int ldbt2,
    long long btStrideZ, long long bstride,
    const float* __restrict__ bias, const float* __restrict__ bias2,
    const float* __restrict__ scale,
    const float* __restrict__ tbias, const ushort_t* __restrict__ resid,
    const ushort_t* __restrict__ part1,
    float* __restrict__ Cf, ushort_t* __restrict__ Cb, ushort_t* __restrict__ CbT,
    long long cStrideZ) {
    __shared__ ushort_t Ts[64 * 136];
    const int row0 = blockIdx.x * 128;
    const int n0 = blockIdx.y * 64;
    const int z = blockIdx.z;
    const int tid = threadIdx.x;
    const int lane = tid & 63;
    const int w = tid >> 6;
    const int l15 = lane & 15, quad = lane >> 4;
    const int wm = (w >> 1) * 64, wn = (w & 1) * 32;

    const bool reg2 = (n0 >= nsplit);
    const ushort_t* BTu = reg2 ? BT2 : BT;
    const int ldbtu = reg2 ? ldbt2 : ldbt;
    const int n0u = reg2 ? (n0 - nsplit) : n0;

    const ushort_t* Abase = A + (size_t)z * aStrideZ
                            + (size_t)(row0 + wm + l15) * lda + quad * 8;
    const ushort_t* Bbase = BTu + (size_t)z * btStrideZ
                            + (size_t)(row0 >> 9) * (size_t)bstride
                            + (size_t)(n0u + wn + l15) * ldbtu + quad * 8;
    const ushort_t* aP0 = Abase;
    const ushort_t* aP1 = Abase + (size_t)16 * lda;
    const ushort_t* aP2 = Abase + (size_t)32 * lda;
    const ushort_t* aP3 = Abase + (size_t)48 * lda;
    const ushort_t* bP0 = Bbase;
    const ushort_t* bP1 = Bbase + (size_t)16 * ldbtu;

    floatx4 acc[4][2];
#pragma unroll
    for (int i = 0; i < 4; i++)
#pragma unroll
        for (int j = 0; j < 2; j++) {
            acc[i][j][0] = 0.0f; acc[i][j][1] = 0.0f;
            acc[i][j][2] = 0.0f; acc[i][j][3] = 0.0f;
        }

#pragma unroll
    for (int kc = 0; kc < K; kc += 32) {
        short8 af0 = *(const short8*)(aP0 + kc);
        short8 af1 = *(const short8*)(aP1 + kc);
        short8 af2 = *(const short8*)(aP2 + kc);
        short8 af3 = *(const short8*)(aP3 + kc);
        short8 bf0 = *(const short8*)(bP0 + kc);
        short8 bf1 = *(const short8*)(bP1 + kc);
        acc[0][0] = __builtin_amdgcn_mfma_f32_16x16x32_bf16(af0, bf0, acc[0][0], 0, 0, 0);
        acc[0][1] = __builtin_amdgcn_mfma_f32_16x16x32_bf16(af0, bf1, acc[0][1], 0, 0, 0);
        acc[1][0] = __builtin_amdgcn_mfma_f32_16x16x32_bf16(af1, bf0, acc[1][0], 0, 0, 0);
        acc[1][1] = __builtin_amdgcn_mfma_f32_16x16x32_bf16(af1, bf1, acc[1][1], 0, 0, 0);
        acc[2][0] = __builtin_amdgcn_mfma_f32_16x16x32_bf16(af2, bf0, acc[2][0], 0, 0, 0);
        acc[2][1] = __builtin_amdgcn_mfma_f32_16x16x32_bf16(af2, bf1, acc[2][1], 0, 0, 0);
        acc[3][0] = __builtin_amdgcn_mfma_f32_16x16x32_bf16(af3, bf0, acc[3][0], 0, 0, 0);
        acc[3][1] = __builtin_amdgcn_mfma_f32_16x16x32_bf16(af3, bf1, acc[3][1], 0, 0, 0);
    }

    if (reg2) {
        // transposed epilogue: acc -> Ts[col][m] -> coalesced per-batch store
#pragma unroll
        for (int tm = 0; tm < 4; tm++)
#pragma unroll
            for (int tn = 0; tn < 2; tn++)
#pragma unroll
                for (int r = 0; r < 4; r++) {
                    const int ml = wm + tm * 16 + quad * 4 + r;
                    const int cl = wn + tn * 16 + l15;
                    float v = acc[tm][tn][r];
                    if (bias2) v += bias2[n0u + cl];
                    Ts[cl * 136 + ml] = f2bf(v);
                }
        __syncthreads();
        const int cl = tid >> 2, ch = (tid & 3) * 32;
        const int b = row0 >> 9;
        ushort_t* dst = CbT + (size_t)b * NN * HH + (size_t)(n0u + cl) * NN + (row0 & 511) + ch;
        uint4 u0 = *(const uint4*)&Ts[cl * 136 + ch];
        uint4 u1 = *(const uint4*)&Ts[cl * 136 + ch + 8];
        uint4 u2 = *(const uint4*)&Ts[cl * 136 + ch + 16];
        uint4 u3 = *(const uint4*)&Ts[cl * 136 + ch + 24];
        *(uint4*)(dst)      = u0;
        *(uint4*)(dst + 8)  = u1;
        *(uint4*)(dst + 16) = u2;
        *(uint4*)(dst + 24) = u3;
        return;
    }

#pragma unroll
    for (int tm = 0; tm < 4; tm++)
#pragma unroll
        for (int tn = 0; tn < 2; tn++) {
#pragma unroll
            for (int r = 0; r < 4; r++) {
                const int row = row0 + wm + tm * 16 + quad * 4 + r;
                const int col = n0 + wn + tn * 16 + l15;
                float v = acc[tm][tn][r];
                if (scale) v *= scale[row];
                if (bias) v += bias[col];
                if (part1) v += bf2f(part1[(size_t)row * HH + col]);
                if (tbias) v += tbias[((row >> 9) << 8) + col] + bf2f(resid[(size_t)row * HH + col]);
                if (Cf) Cf[(size_t)row * HH + col] = v;
                if (Cb) Cb[(size_t)z * cStrideZ + (size_t)row * HH + col] = f2bf(v);
            }
        }
}

// ---------- 7) layernorm: wave-per-row, no barriers; grid 4096 ----------
__global__ __launch_bounds__(256) void ln_kernel(
    const float* __restrict__ pre, const float* __restrict__ g,
    const float* __restrict__ b, ushort_t* __restrict__ h_bf) {
    const int row = blockIdx.x * 4 + (threadIdx.x >> 6);
    const int lane = threadIdx.x & 63;
    const float* pr = pre + (size_t)row * HH;
    float4 x = ((const float4*)pr)[lane];
    float s = x.x + x.y + x.z + x.w;
    float q = x.x * x.x + x.y * x.y + x.z * x.z + x.w * x.w;
#pragma unroll
    for (int o = 32; o > 0; o >>= 1) {
        s += __shfl_xor(s, o, 64);
        q += __shfl_xor(q, o, 64);
    }
    float mu = s * (1.0f / HH);
    float var = q * (1.0f / HH) - mu * mu;
    float rs = rsqrtf(var + 1e-5f);
    float4 gv = ((const float4*)g)[lane];
    float4 bv = ((const float4*)b)[lane];
    uint2 pk;
    pk.x = (u32)f2bf((x.x - mu) * rs * gv.x + bv.x)
         | ((u32)f2bf((x.y - mu) * rs * gv.y + bv.y) << 16);
    pk.y = (u32)f2bf((x.z - mu) * rs * gv.z + bv.z)
         | ((u32)f2bf((x.w - mu) * rs * gv.w + bv.w) << 16);
    *(uint2*)(h_bf + (size_t)row * HH + lane * 4) = pk;
}

// ---------- 8) partial h_graph sums ----------
__global__ __launch_bounds__(256) void psum_kernel(
    const ushort_t* __restrict__ h_bf, float* __restrict__ partial) {
    const int b = blockIdx.x, ch = blockIdx.y, tid = threadIdx.x;
    const ushort_t* hp = h_bf + ((size_t)b * NN + ch * 32) * HH;
    float s = 0.0f;
#pragma unroll
    for (int i = 0; i < 32; i++) s += bf2f(hp[i * HH + tid]);
    partial[(((size_t)b * 16 + ch) << 8) + tid] = s;
}

// ---------- 9) h_graph reduce + first proj + silu -> sT[h][b] ----------
__global__ __launch_bounds__(256) void final_kernel(
    const float* __restrict__ partial, const float* __restrict__ op_W1,
    const float* __restrict__ op_b1, float* __restrict__ sT) {
    int b = blockIdx.x, tid = threadIdx.x;
    __shared__ float hg[HH];
    float acc = 0.0f;
#pragma unroll
    for (int c = 0; c < 16; c++) acc += partial[(((size_t)b * 16 + c) << 8) + tid];
    hg[tid] = acc;
    __syncthreads();
    float o = op_b1[tid];
#pragma unroll 8
    for (int k = 0; k < HH; k++) o = fmaf(hg[k], op_W1[k * HH + tid], o);
    sT[tid * BB + b] = o / (1.0f + expf(-o));
}

// ---------- 10) fused second proj + triu target + MSE (NE = 511*256) ----------
__global__ __launch_bounds__(256) void loss_kernel(
    const float* __restrict__ sT, const float* __restrict__ op_W2,
    const float* __restrict__ op_b2, const float* __restrict__ noise,
    float* __restrict__ out) {
    __shared__ float red[4];
    const int tid = threadIdx.x;
    const int e = blockIdx.x * 256 + tid;
    float lsum = 0.0f;
    float acc[32];
#pragma unroll
    for (int b = 0; b < 32; b++) acc[b] = 0.0f;
    const float* w2 = op_W2 + e;
#pragma unroll 16
    for (int h = 0; h < 256; h++) {
        float wv = w2[(size_t)h * NE];
        const float* sr = sT + h * BB;   // block-uniform -> s_load
#pragma unroll
        for (int b = 0; b < 32; b++) acc[b] = fmaf(sr[b], wv, acc[b]);
    }
    int i = (int)((1023.0 - sqrt(1046529.0 - 8.0 * (double)e)) * 0.5);
    if (i < 0) i = 0;
    if (i > 510) i = 510;
    while (i > 0 && (i * (1023 - i)) / 2 > e) --i;
    while (((i + 1) * (1022 - i)) / 2 <= e) ++i;
    int j = i + 1 + (e - (i * (1023 - i)) / 2);
    const float pb = op_b2[e];
    const float* np = noise + (size_t)i * NN + j;
#pragma unroll
    for (int b = 0; b < 32; b++) {
        float d = acc[b] + pb - np[(size_t)b * NN * NN];
        lsum += d * d;
    }
    lsum *= (1.0f / (32.0f * (float)NE));
    lsum = block_reduce_sum256(lsum, red);
    if (tid == 0) atomicAdd(out, lsum);
}

// ---------- launch ----------
extern "C" void kernel_launch(void* const* d_in, const int* in_sizes, int n_in,
                              void* d_out, int out_size, void* d_ws, size_t ws_size,
                              hipStream_t stream) {
    const float* adj0  = (const float*)d_in[0];
    const float* noise = (const float*)d_in[1];
    const float* te_W1 = (const float*)d_in[2];
    const float* te_b1 = (const float*)d_in[3];
    const float* te_W2 = (const float*)d_in[4];
    const float* te_b2 = (const float*)d_in[5];
    const float* ip_W  = (const float*)d_in[6];
    const float* ip_b  = (const float*)d_in[7];
    const float* msg_W = (const float*)d_in[8];
    const float* msg_b = (const float*)d_in[9];
    const float* upd_W = (const float*)d_in[10];
    const float* upd_b = (const float*)d_in[11];
    const float* ln_g  = (const float*)d_in[12];
    const float* ln_b  = (const float*)d_in[13];
    const float* tp_W  = (const float*)d_in[14];
    const float* tp_b  = (const float*)d_in[15];
    const float* op_W1 = (const float*)d_in[16];
    const float* op_b1 = (const float*)d_in[17];
    const float* op_W2 = (const float*)d_in[18];
    const float* op_b2 = (const float*)d_in[19];
    const int*   t     = (const int*)d_in[20];
    float* out = (float*)d_out;

    float* ws = (float*)d_ws;
    float* sched   = ws;                    // 256
    float* tbias   = ws + 256;              // 32768
    float* invrs   = ws + 33024;            // 16384
    float* sbuf    = ws + 49408;            // 8192 (sT: 256x32)
    float* embb    = ws + 57600;            // 8192
    float* bfv     = ws + 65792;            // 1024
    float* partial = ws + 66816;            // 131072
    float* pre     = ws + 197888;           // 4194304
    ushort_t* bfb  = (ushort_t*)(ws + 4392192);
    ushort_t* adjt_bf = bfb;                // 8388608
    ushort_t* h_bf    = bfb + 8388608;      // 4194304
    ushort_t* part1   = bfb + 12582912;     // 4194304
    ushort_t* hm2T    = bfb + 16777216;     // 4194304 (per-batch [256][512])
    ushort_t* ipWT    = bfb + 20971520;     // 131072
    ushort_t* msgWbf  = bfb + 21102592;     // 262144
    ushort_t* updWT   = bfb + 21364736;     // 524288
    ushort_t* WfT     = bfb + 21889024;     // 262144

    const int NS_OFF = 1 << 30;

    init_kernel<<<1, 128, 0, stream>>>(sched, out);
    wcvt_kernel<<<dim3(8, 16, 9), 256, 0, stream>>>(ip_W, msg_W, upd_W, ipWT, msgWbf, updWT);
    bfv_kernel<<<4, 256, 0, stream>>>(msg_b, upd_W, bfv);
    temb1_kernel<<<dim3(32, 4), 256, 0, stream>>>(te_W1, te_b1, te_W2, te_b2, t, embb);
    temb2_kernel<<<dim3(32, 16), 256, 0, stream>>>(embb, tp_W, tp_b, tbias);
    adj_kernel<<<4096, 256, 0, stream>>>(adj0, noise, t, sched, adjt_bf, invrs);

    // WfT[l] = Wu2[l]^T @ Wm[l]^T  (z-batched over 4 layers)
    gemm_nolds<256><<<dim3(2, 4, 4), 256, 0, stream>>>(
        NS_OFF,
        updWT + 256, 512, 131072,
        msgWbf, 256, nullptr, 0, 65536, 0,
        nullptr, nullptr, nullptr, nullptr, nullptr, nullptr,
        nullptr, WfT, nullptr, 65536);

    // h = bf16(adj_t @ ip_W + ip_b)
    gemm_nolds<512><<<dim3(128, 4), 256, 0, stream>>>(
        NS_OFF,
        adjt_bf, 512, 0,
        ipWT, 512, nullptr, 0, 0, 0,
        ip_b, nullptr, nullptr, nullptr, nullptr, nullptr,
        nullptr, h_bf, nullptr, 0);

    for (int l = 0; l < 4; l++) {
        // [part1 | hm2T] = h @ [Wu1 | Wf]  (N=512 fused; cols>=256 -> transposed +bfv)
        gemm_nolds<256><<<dim3(128, 8), 256, 0, stream>>>(
            256,
            h_bf, 256, 0,
            updWT + l * 131072, 512,
            WfT + l * 65536, 256, 0, 0,
            nullptr, bfv + l * 256, nullptr, nullptr, nullptr, nullptr,
            nullptr, part1, hm2T, 0);
        // pre = invrs*(adj_t @ hm2[b]) + part1 + upd_b + tbias + h
        gemm_nolds<512><<<dim3(128, 4), 256, 0, stream>>>(
            NS_OFF,
            adjt_bf, 512, 0,
            hm2T, 512, nullptr, 0, 0, (long long)(HH * NN),
            upd_b + l * HH, nullptr, invrs,
            tbias + l * BB * HH, h_bf, part1,
            pre, nullptr, nullptr, 0);
        // h = bf16(LN(pre)*g + b)
        ln_kernel<<<4096, 256, 0, stream>>>(pre, ln_g + l * HH, ln_b + l * HH, h_bf);
    }
    psum_kernel<<<dim3(32, 16), 256, 0, stream>>>(h_bf, partial);
    final_kernel<<<32, 256, 0, stream>>>(partial, op_W1, op_b1, sbuf);
    loss_kernel<<<511, 256, 0, stream>>>(sbuf, op_W2, op_b2, noise, out);
}

// Round 7
// 542.398 us; speedup vs baseline: 1.3789x; 1.3789x over previous
//
#include <hip/hip_runtime.h>
#include <math.h>

#define NN 512
#define HH 256
#define BB 32
#define NE 130816

typedef unsigned short ushort_t;
typedef unsigned int u32;
using short8  = __attribute__((ext_vector_type(8))) short;
using floatx4 = __attribute__((ext_vector_type(4))) float;

typedef __attribute__((address_space(3))) u32* lds_u32p;
typedef const __attribute__((address_space(1))) u32* glb_u32p;

// ---------- bf16 helpers (RNE) ----------
__device__ inline unsigned short f2bf(float f) {
    unsigned int u = __float_as_uint(f);
    unsigned int r = (u + 0x7fffu + ((u >> 16) & 1u)) >> 16;
    return (unsigned short)r;
}
__device__ inline float bf2f(unsigned short x) {
    return __uint_as_float(((unsigned int)x) << 16);
}

// ---------- reduction helpers ----------
__device__ inline float wave_reduce_sum(float v) {
#pragma unroll
    for (int o = 32; o > 0; o >>= 1) v += __shfl_xor(v, o, 64);
    return v;
}
__device__ inline float block_reduce_sum256(float v, float* red) {
    v = wave_reduce_sum(v);
    int w = threadIdx.x >> 6;
    if ((threadIdx.x & 63) == 0) red[w] = v;
    __syncthreads();
    v = red[0] + red[1] + red[2] + red[3];
    __syncthreads();
    return v;
}

// ---------- 1) schedule init + out zero ----------
__global__ void init_kernel(float* __restrict__ sched, float* __restrict__ out) {
    __shared__ float alpha_s[100];
    int tid = threadIdx.x;
    if (tid < 100) {
        const double PI_H = 3.14159265358979323846 * 0.5;
        double f1 = (((double)tid / 100.0) + 0.008) / 1.008 * PI_H;
        double f2 = (((double)(tid + 1) / 100.0) + 0.008) / 1.008 * PI_H;
        double c1 = cos(f1), c2 = cos(f2);
        double beta = 1.0 - (c2 * c2) / (c1 * c1);
        if (beta > 0.999) beta = 0.999;
        alpha_s[tid] = 1.0f - (float)beta;
    }
    __syncthreads();
    if (tid == 0) {
        out[0] = 0.0f;
        float cum = 1.0f;
        for (int k = 0; k < 100; k++) {
            cum *= alpha_s[k];
            sched[k]       = sqrtf(cum);
            sched[100 + k] = sqrtf(1.0f - cum);
        }
    }
}

// ---------- 2a) emb = silu(tf@W1+b1)@W2 + b2 ----------
__global__ __launch_bounds__(256) void temb1_kernel(
    const float* __restrict__ te_W1, const float* __restrict__ te_b1,
    const float* __restrict__ te_W2, const float* __restrict__ te_b2,
    const int* __restrict__ t, float* __restrict__ emb_out) {
    const int b = blockIdx.x, cb = blockIdx.y * 64, tid = threadIdx.x;
    __shared__ float hid[HH];
    __shared__ float part[4][64];
    float tf = (float)t[b] / 100.0f;
    float z = tf * te_W1[tid] + te_b1[tid];
    hid[tid] = z / (1.0f + expf(-z));
    __syncthreads();
    const int col = tid & 63, kc = tid >> 6;
    float a = 0.0f;
#pragma unroll 8
    for (int k0 = 0; k0 < 64; k0++) {
        int k = kc * 64 + k0;
        a = fmaf(hid[k], te_W2[k * HH + cb + col], a);
    }
    part[kc][col] = a;
    __syncthreads();
    if (kc == 0) {
        float o = part[0][col] + part[1][col] + part[2][col] + part[3][col] + te_b2[cb + col];
        emb_out[b * HH + cb + col] = o;
    }
}

// ---------- 2b) tbias[l,b,:] = emb[b]@tp_W[l] + tp_b[l] ----------
__global__ __launch_bounds__(256) void temb2_kernel(
    const float* __restrict__ emb, const float* __restrict__ tp_W,
    const float* __restrict__ tp_b, float* __restrict__ tbias_out) {
    const int b = blockIdx.x;
    const int l = blockIdx.y >> 2, cb = (blockIdx.y & 3) * 64;
    const int tid = threadIdx.x;
    __shared__ float es[HH];
    __shared__ float part[4][64];
    es[tid] = emb[b * HH + tid];
    __syncthreads();
    const int col = tid & 63, kc = tid >> 6;
    const float* W = tp_W + l * HH * HH;
    float a = 0.0f;
#pragma unroll 8
    for (int k0 = 0; k0 < 64; k0++) {
        int k = kc * 64 + k0;
        a = fmaf(es[k], W[k * HH + cb + col], a);
    }
    part[kc][col] = a;
    __syncthreads();
    if (kc == 0) {
        float o = part[0][col] + part[1][col] + part[2][col] + part[3][col]
                + tp_b[l * HH + cb + col];
        tbias_out[l * (BB * HH) + b * HH + cb + col] = o;
    }
}

// ---------- 3) adj_t (bf16) + inverse row abs-sum; wave-per-row ----------
__global__ __launch_bounds__(256) void adj_kernel(
    const float* __restrict__ adj0, const float* __restrict__ noise,
    const int* __restrict__ t, const float* __restrict__ sched,
    ushort_t* __restrict__ adjt_bf, float* __restrict__ invrs) {
    const int row = blockIdx.x * 4 + (threadIdx.x >> 6);
    const int lane = threadIdx.x & 63;
    const int b = row >> 9;
    const int ts = t[b];
    const float sab = sched[ts], som = sched[100 + ts];
    const size_t base = (size_t)row * NN + lane * 8;
    float4 a0 = *(const float4*)(adj0 + base);
    float4 a1 = *(const float4*)(adj0 + base + 4);
    float4 q0 = *(const float4*)(noise + base);
    float4 q1 = *(const float4*)(noise + base + 4);
    float v0 = fmaf(sab, a0.x, som * q0.x), v1 = fmaf(sab, a0.y, som * q0.y);
    float v2 = fmaf(sab, a0.z, som * q0.z), v3 = fmaf(sab, a0.w, som * q0.w);
    float v4 = fmaf(sab, a1.x, som * q1.x), v5 = fmaf(sab, a1.y, som * q1.y);
    float v6 = fmaf(sab, a1.z, som * q1.z), v7 = fmaf(sab, a1.w, som * q1.w);
    uint4 pk;
    pk.x = (u32)f2bf(v0) | ((u32)f2bf(v1) << 16);
    pk.y = (u32)f2bf(v2) | ((u32)f2bf(v3) << 16);
    pk.z = (u32)f2bf(v4) | ((u32)f2bf(v5) << 16);
    pk.w = (u32)f2bf(v6) | ((u32)f2bf(v7) << 16);
    *(uint4*)(adjt_bf + base) = pk;
    float s = fabsf(v0) + fabsf(v1) + fabsf(v2) + fabsf(v3)
            + fabsf(v4) + fabsf(v5) + fabsf(v6) + fabsf(v7);
    s = wave_reduce_sum(s);
    if (lane == 0) invrs[row] = 1.0f / (s + 1.0f);
}

// ---------- 4) weight convert ----------
__global__ __launch_bounds__(256) void wcvt_kernel(
    const float* __restrict__ ip_W, const float* __restrict__ msg_W,
    const float* __restrict__ upd_W,
    ushort_t* __restrict__ ipWT, ushort_t* __restrict__ msgWbf,
    ushort_t* __restrict__ updWT) {
    const int z = blockIdx.z;
    const int r0 = blockIdx.y * 32, c0 = blockIdx.x * 32;
    const int tr = threadIdx.x >> 5, tc = threadIdx.x & 31;
    if (z >= 1 && z <= 4) {
        const float* src = msg_W + (z - 1) * 65536;
        ushort_t* dst = msgWbf + (z - 1) * 65536;
        if (r0 >= 256) return;
#pragma unroll
        for (int s = 0; s < 32; s += 8)
            dst[(size_t)(r0 + tr + s) * 256 + c0 + tc] =
                f2bf(src[(size_t)(r0 + tr + s) * 256 + c0 + tc]);
        return;
    }
    const float* src; ushort_t* dst; int R;
    if (z == 0) { src = ip_W;                     dst = ipWT;                     R = 512; }
    else        { src = upd_W + (z - 5) * 131072; dst = updWT + (z - 5) * 131072; R = 512; }
    __shared__ float T[32][33];
#pragma unroll
    for (int s = 0; s < 32; s += 8)
        T[tr + s][tc] = src[(size_t)(r0 + tr + s) * 256 + c0 + tc];
    __syncthreads();
#pragma unroll
    for (int s = 0; s < 32; s += 8)
        dst[(size_t)(c0 + tr + s) * R + r0 + tc] = f2bf(T[tc][tr + s]);
}

// ---------- 5) bfv[l] = msg_b[l] @ Wu2[l]  (fp32) ----------
__global__ __launch_bounds__(256) void bfv_kernel(
    const float* __restrict__ msg_b, const float* __restrict__ upd_W,
    float* __restrict__ bfv) {
    const int l = blockIdx.x, n = threadIdx.x;
    float a = 0.0f;
#pragma unroll 8
    for (int j = 0; j < 256; j++)
        a = fmaf(msg_b[l * 256 + j], upd_W[(size_t)l * 131072 + (size_t)(256 + j) * 256 + n], a);
    bfv[l * 256 + n] = a;
}

// ---------- 6) LDS-staged bf16 MFMA GEMM, tile 128x64; n-tile FASTEST ----------
// grid: x = n-tile (consecutive blocks share the A-tile -> L2), y = row-tile, z = batch.
// Region split at nsplit: n0 < nsplit -> BT/ldbt, row-major bf16 store (+bias);
//   n0 >= nsplit -> BT2/ldbt2 (+bias2), per-512-row-batch transposed store to CbT.
__global__ __launch_bounds__(256, 2) void gemm_tile(
    int K, int nsplit,
    const ushort_t* __restrict__ A, int lda, long long aStrideZ,
    const ushort_t* __restrict__ BT, int ldbt,
    const ushort_t* __restrict__ BT2, int ldbt2, long long btStrideZ,
    const float* __restrict__ bias, const float* __restrict__ bias2,
    ushort_t* __restrict__ Cb, ushort_t* __restrict__ CbT, long long cStrideZ) {
    __shared__ ushort_t As[128 * 32];
    __shared__ ushort_t Bs[64 * 32];
    __shared__ ushort_t Ts[64 * 136];
    const int n0 = blockIdx.x * 64;
    const int row0 = blockIdx.y * 128;
    const int z = blockIdx.z;
    const int tid = threadIdx.x;
    const int lane = tid & 63;
    const int w = tid >> 6;
    const int l15 = lane & 15, quad = lane >> 4;
    const int wm = (w >> 1) * 64, wn = (w & 1) * 32;

    const bool reg2 = (n0 >= nsplit);
    const ushort_t* BTu = reg2 ? BT2 : BT;
    const int ldbtu = reg2 ? ldbt2 : ldbt;
    const int n0u = reg2 ? (n0 - nsplit) : n0;
    const ushort_t* Az = A + (size_t)z * aStrideZ;
    const ushort_t* Bp = BTu + (size_t)z * btStrideZ;

    const int srow = lane >> 2;
    const int gkoff = (((lane & 3) ^ (lane >> 4)) << 3);
    const int swz = ((quad ^ ((l15 >> 2) & 3)) << 3);

    floatx4 acc[4][2];
#pragma unroll
    for (int i = 0; i < 4; i++)
#pragma unroll
        for (int j = 0; j < 2; j++) {
            acc[i][j][0] = 0.0f; acc[i][j][1] = 0.0f;
            acc[i][j][2] = 0.0f; acc[i][j][3] = 0.0f;
        }

    for (int kc = 0; kc < K; kc += 32) {
#pragma unroll
        for (int r = 0; r < 2; r++) {
            const int lbase = (r * 4 + w) * 16;
            const ushort_t* gpA = Az + (size_t)(row0 + lbase + srow) * lda + kc + gkoff;
            __builtin_amdgcn_global_load_lds((glb_u32p)(const void*)gpA,
                                             (lds_u32p)(void*)&As[lbase * 32], 16, 0, 0);
        }
        {
            const int lbase = w * 16;
            const ushort_t* gpB = Bp + (size_t)(n0u + lbase + srow) * ldbtu + kc + gkoff;
            __builtin_amdgcn_global_load_lds((glb_u32p)(const void*)gpB,
                                             (lds_u32p)(void*)&Bs[lbase * 32], 16, 0, 0);
        }
        __syncthreads();

        short8 af[4], bfr[2];
#pragma unroll
        for (int tm = 0; tm < 4; tm++)
            af[tm] = *(const short8*)&As[(wm + tm * 16 + l15) * 32 + swz];
#pragma unroll
        for (int tn = 0; tn < 2; tn++)
            bfr[tn] = *(const short8*)&Bs[(wn + tn * 16 + l15) * 32 + swz];
#pragma unroll
        for (int tm = 0; tm < 4; tm++)
#pragma unroll
            for (int tn = 0; tn < 2; tn++)
                acc[tm][tn] = __builtin_amdgcn_mfma_f32_16x16x32_bf16(
                    af[tm], bfr[tn], acc[tm][tn], 0, 0, 0);
        __syncthreads();
    }

    if (reg2) {
#pragma unroll
        for (int tm = 0; tm < 4; tm++)
#pragma unroll
            for (int tn = 0; tn < 2; tn++)
#pragma unroll
                for (int r = 0; r < 4; r++) {
                    const int ml = wm + tm * 16 + quad * 4 + r;
                    const int cl = wn + tn * 16 + l15;
                    float v = acc[tm][tn][r];
                    if (bias2) v += bias2[n0u + cl];
                    Ts[cl * 136 + ml] = f2bf(v);
                }
        __syncthreads();
        const int cl = tid >> 2, ch = (tid & 3) * 32;
        const int b = row0 >> 9;
        ushort_t* dst = CbT + (size_t)b * NN * HH + (size_t)(n0u + cl) * NN + (row0 & 511) + ch;
        uint4 u0 = *(const uint4*)&Ts[cl * 136 + ch];
        uint4 u1 = *(const uint4*)&Ts[cl * 136 + ch + 8];
        uint4 u2 = *(const uint4*)&Ts[cl * 136 + ch + 16];
        uint4 u3 = *(const uint4*)&Ts[cl * 136 + ch + 24];
        *(uint4*)(dst)      = u0;
        *(uint4*)(dst + 8)  = u1;
        *(uint4*)(dst + 16) = u2;
        *(uint4*)(dst + 24) = u3;
        return;
    }

#pragma unroll
    for (int tm = 0; tm < 4; tm++)
#pragma unroll
        for (int tn = 0; tn < 2; tn++) {
#pragma unroll
            for (int r = 0; r < 4; r++) {
                const int row = row0 + wm + tm * 16 + quad * 4 + r;
                const int col = n0 + wn + tn * 16 + l15;
                float v = acc[tm][tn][r];
                if (bias) v += bias[col];
                Cb[(size_t)z * cStrideZ + (size_t)row * HH + col] = f2bf(v);
            }
        }
}

// ---------- 7) fused GEMM + epilogue + LayerNorm, tile 32x256 (full N) ----------
// h_bf := bf16( LN( invrs[row]*(adjt @ hm2[b])[row,col] + upd_b[col] + tbias[b,col]
//                   + part1[row,col] + h_bf[row,col] ) * g + b )    (in-place h)
__global__ __launch_bounds__(256, 2) void gemm_preln(
    const ushort_t* __restrict__ A,      // adjt [16384][512]
    const ushort_t* __restrict__ BT,     // hm2T [32][256][512]
    const float* __restrict__ invrs,
    const float* __restrict__ upd_b,
    const float* __restrict__ tbias,     // [32][256] (layer pre-offset)
    const ushort_t* __restrict__ part1,  // [16384][256] bf16
    const float* __restrict__ ln_g, const float* __restrict__ ln_b,
    ushort_t* __restrict__ h_bf) {       // in/out [16384][256]
    __shared__ ushort_t As[32 * 32];     // 2 KB
    __shared__ ushort_t Bs[256 * 32];    // 16 KB
    __shared__ float rsum[32][4];
    __shared__ float rsq[32][4];
    const int row0 = blockIdx.x * 32;
    const int b = row0 >> 9;
    const int tid = threadIdx.x;
    const int lane = tid & 63;
    const int w = tid >> 6;
    const int l15 = lane & 15, quad = lane >> 4;
    const int wn = w * 64;
    const int srow = lane >> 2;
    const int gkoff = (((lane & 3) ^ (lane >> 4)) << 3);
    const int swz = ((quad ^ ((l15 >> 2) & 3)) << 3);
    const ushort_t* Bb = BT + (size_t)b * (HH * NN);

    floatx4 acc[2][4];
#pragma unroll
    for (int i = 0; i < 2; i++)
#pragma unroll
        for (int j = 0; j < 4; j++) {
            acc[i][j][0] = 0.0f; acc[i][j][1] = 0.0f;
            acc[i][j][2] = 0.0f; acc[i][j][3] = 0.0f;
        }

    for (int kc = 0; kc < 512; kc += 32) {
        if (w < 2) {   // A: 32 rows
            const ushort_t* gpA = A + (size_t)(row0 + w * 16 + srow) * 512 + kc + gkoff;
            __builtin_amdgcn_global_load_lds((glb_u32p)(const void*)gpA,
                                             (lds_u32p)(void*)&As[(w * 16) * 32], 16, 0, 0);
        }
#pragma unroll
        for (int r = 0; r < 4; r++) {  // B: 256 n-rows
            const int nb = r * 64 + w * 16;
            const ushort_t* gpB = Bb + (size_t)(nb + srow) * 512 + kc + gkoff;
            __builtin_amdgcn_global_load_lds((glb_u32p)(const void*)gpB,
                                             (lds_u32p)(void*)&Bs[nb * 32], 16, 0, 0);
        }
        __syncthreads();

        short8 af[2], bfr[4];
#pragma unroll
        for (int tm = 0; tm < 2; tm++)
            af[tm] = *(const short8*)&As[(tm * 16 + l15) * 32 + swz];
#pragma unroll
        for (int tn = 0; tn < 4; tn++)
            bfr[tn] = *(const short8*)&Bs[(wn + tn * 16 + l15) * 32 + swz];
#pragma unroll
        for (int tm = 0; tm < 2; tm++)
#pragma unroll
            for (int tn = 0; tn < 4; tn++)
                acc[tm][tn] = __builtin_amdgcn_mfma_f32_16x16x32_bf16(
                    af[tm], bfr[tn], acc[tm][tn], 0, 0, 0);
        __syncthreads();
    }

    // epilogue: full pre-LN value, per-row stats, then LN
    float ev[2][4][4];
    float ps[2][4], pq[2][4];
#pragma unroll
    for (int tm = 0; tm < 2; tm++)
#pragma unroll
        for (int r = 0; r < 4; r++) { ps[tm][r] = 0.0f; pq[tm][r] = 0.0f; }
#pragma unroll
    for (int tm = 0; tm < 2; tm++)
#pragma unroll
        for (int r = 0; r < 4; r++) {
            const int row = row0 + tm * 16 + quad * 4 + r;
            const float iv = invrs[row];
#pragma unroll
            for (int tn = 0; tn < 4; tn++) {
                const int col = wn + tn * 16 + l15;
                float v = acc[tm][tn][r] * iv + upd_b[col] + tbias[(b << 8) + col]
                        + bf2f(part1[(size_t)row * HH + col])
                        + bf2f(h_bf[(size_t)row * HH + col]);
                ev[tm][tn][r] = v;
                ps[tm][r] += v;
                pq[tm][r] += v * v;
            }
        }
#pragma unroll
    for (int o = 1; o < 16; o <<= 1) {
#pragma unroll
        for (int tm = 0; tm < 2; tm++)
#pragma unroll
            for (int r = 0; r < 4; r++) {
                ps[tm][r] += __shfl_xor(ps[tm][r], o, 64);
                pq[tm][r] += __shfl_xor(pq[tm][r], o, 64);
            }
    }
    if (l15 == 0) {
#pragma unroll
        for (int tm = 0; tm < 2; tm++)
#pragma unroll
            for (int r = 0; r < 4; r++) {
                rsum[tm * 16 + quad * 4 + r][w] = ps[tm][r];
                rsq[tm * 16 + quad * 4 + r][w] = pq[tm][r];
            }
    }
    __syncthreads();
#pragma unroll
    for (int tm = 0; tm < 2; tm++)
#pragma unroll
        for (int r = 0; r < 4; r++) {
            const int rl = tm * 16 + quad * 4 + r;
            const int row = row0 + rl;
            float s = rsum[rl][0] + rsum[rl][1] + rsum[rl][2] + rsum[rl][3];
            float q = rsq[rl][0] + rsq[rl][1] + rsq[rl][2] + rsq[rl][3];
            float mu = s * (1.0f / HH);
            float var = q * (1.0f / HH) - mu * mu;
            float rs = rsqrtf(var + 1e-5f);
#pragma unroll
            for (int tn = 0; tn < 4; tn++) {
                const int col = wn + tn * 16 + l15;
                float o = (ev[tm][tn][r] - mu) * rs * ln_g[col] + ln_b[col];
                h_bf[(size_t)row * HH + col] = f2bf(o);
            }
        }
}

// ---------- 8) partial h_graph sums ----------
__global__ __launch_bounds__(256) void psum_kernel(
    const ushort_t* __restrict__ h_bf, float* __restrict__ partial) {
    const int b = blockIdx.x, ch = blockIdx.y, tid = threadIdx.x;
    const ushort_t* hp = h_bf + ((size_t)b * NN + ch * 32) * HH;
    float s = 0.0f;
#pragma unroll
    for (int i = 0; i < 32; i++) s += bf2f(hp[i * HH + tid]);
    partial[(((size_t)b * 16 + ch) << 8) + tid] = s;
}

// ---------- 9) h_graph reduce + first proj + silu -> sT[h][b] ----------
__global__ __launch_bounds__(256) void final_kernel(
    const float* __restrict__ partial, const float* __restrict__ op_W1,
    const float* __restrict__ op_b1, float* __restrict__ sT) {
    int b = blockIdx.x, tid = threadIdx.x;
    __shared__ float hg[HH];
    float acc = 0.0f;
#pragma unroll
    for (int c = 0; c < 16; c++) acc += partial[(((size_t)b * 16 + c) << 8) + tid];
    hg[tid] = acc;
    __syncthreads();
    float o = op_b1[tid];
#pragma unroll 8
    for (int k = 0; k < HH; k++) o = fmaf(hg[k], op_W1[k * HH + tid], o);
    sT[tid * BB + b] = o / (1.0f + expf(-o));
}

// ---------- 10) fused second proj + triu target + MSE ----------
// Batched loads: 16 independent w2 loads issued before their FMA block.
__global__ __launch_bounds__(256) void loss_kernel(
    const float* __restrict__ sT, const float* __restrict__ op_W2,
    const float* __restrict__ op_b2, const float* __restrict__ noise,
    float* __restrict__ out) {
    __shared__ float red[4];
    const int tid = threadIdx.x;
    const int e = blockIdx.x * 256 + tid;
    float lsum = 0.0f;
    float acc[32];
#pragma unroll
    for (int b = 0; b < 32; b++) acc[b] = 0.0f;
    const float* w2 = op_W2 + e;
    for (int h0 = 0; h0 < 256; h0 += 16) {
        float wv[16];
#pragma unroll
        for (int u = 0; u < 16; u++)
            wv[u] = w2[(size_t)(h0 + u) * NE];
#pragma unroll
        for (int u = 0; u < 16; u++) {
            const float* sr = sT + (h0 + u) * BB;   // block-uniform -> s_load
#pragma unroll
            for (int b = 0; b < 32; b++) acc[b] = fmaf(sr[b], wv[u], acc[b]);
        }
    }
    int i = (int)((1023.0 - sqrt(1046529.0 - 8.0 * (double)e)) * 0.5);
    if (i < 0) i = 0;
    if (i > 510) i = 510;
    while (i > 0 && (i * (1023 - i)) / 2 > e) --i;
    while (((i + 1) * (1022 - i)) / 2 <= e) ++i;
    int j = i + 1 + (e - (i * (1023 - i)) / 2);
    const float pb = op_b2[e];
    const float* np = noise + (size_t)i * NN + j;
#pragma unroll
    for (int b = 0; b < 32; b++) {
        float d = acc[b] + pb - np[(size_t)b * NN * NN];
        lsum += d * d;
    }
    lsum *= (1.0f / (32.0f * (float)NE));
    lsum = block_reduce_sum256(lsum, red);
    if (tid == 0) atomicAdd(out, lsum);
}

// ---------- launch ----------
extern "C" void kernel_launch(void* const* d_in, const int* in_sizes, int n_in,
                              void* d_out, int out_size, void* d_ws, size_t ws_size,
                              hipStream_t stream) {
    const float* adj0  = (const float*)d_in[0];
    const float* noise = (const float*)d_in[1];
    const float* te_W1 = (const float*)d_in[2];
    const float* te_b1 = (const float*)d_in[3];
    const float* te_W2 = (const float*)d_in[4];
    const float* te_b2 = (const float*)d_in[5];
    const float* ip_W  = (const float*)d_in[6];
    const float* ip_b  = (const float*)d_in[7];
    const float* msg_W = (const float*)d_in[8];
    const float* msg_b = (const float*)d_in[9];
    const float* upd_W = (const float*)d_in[10];
    const float* upd_b = (const float*)d_in[11];
    const float* ln_g  = (const float*)d_in[12];
    const float* ln_b  = (const float*)d_in[13];
    const float* tp_W  = (const float*)d_in[14];
    const float* tp_b  = (const float*)d_in[15];
    const float* op_W1 = (const float*)d_in[16];
    const float* op_b1 = (const float*)d_in[17];
    const float* op_W2 = (const float*)d_in[18];
    const float* op_b2 = (const float*)d_in[19];
    const int*   t     = (const int*)d_in[20];
    float* out = (float*)d_out;

    float* ws = (float*)d_ws;
    float* sched   = ws;                    // 256
    float* tbias   = ws + 256;              // 32768
    float* invrs   = ws + 33024;            // 16384
    float* sbuf    = ws + 49408;            // 8192 (sT)
    float* embb    = ws + 57600;            // 8192
    float* bfv     = ws + 65792;            // 1024
    float* partial = ws + 66816;            // 131072
    ushort_t* bfb  = (ushort_t*)(ws + 197888);
    ushort_t* adjt_bf = bfb;                // 8388608
    ushort_t* h_bf    = bfb + 8388608;      // 4194304
    ushort_t* part1   = bfb + 12582912;     // 4194304
    ushort_t* hm2T    = bfb + 16777216;     // 4194304 (per-batch [256][512])
    ushort_t* ipWT    = bfb + 20971520;     // 131072
    ushort_t* msgWbf  = bfb + 21102592;     // 262144
    ushort_t* updWT   = bfb + 21364736;     // 524288
    ushort_t* WfT     = bfb + 21889024;     // 262144

    const int NS_OFF = 1 << 30;

    init_kernel<<<1, 128, 0, stream>>>(sched, out);
    wcvt_kernel<<<dim3(8, 16, 9), 256, 0, stream>>>(ip_W, msg_W, upd_W, ipWT, msgWbf, updWT);
    bfv_kernel<<<4, 256, 0, stream>>>(msg_b, upd_W, bfv);
    temb1_kernel<<<dim3(32, 4), 256, 0, stream>>>(te_W1, te_b1, te_W2, te_b2, t, embb);
    temb2_kernel<<<dim3(32, 16), 256, 0, stream>>>(embb, tp_W, tp_b, tbias);
    adj_kernel<<<4096, 256, 0, stream>>>(adj0, noise, t, sched, adjt_bf, invrs);

    // WfT[l] = Wu2[l]^T @ Wm[l]^T  (z-batched over 4 layers)
    gemm_tile<<<dim3(4, 2, 4), 256, 0, stream>>>(
        256, NS_OFF,
        updWT + 256, 512, 131072,
        msgWbf, 256, nullptr, 0, 65536,
        nullptr, nullptr,
        WfT, nullptr, 65536);

    // h = bf16(adj_t @ ip_W + ip_b)
    gemm_tile<<<dim3(4, 128), 256, 0, stream>>>(
        512, NS_OFF,
        adjt_bf, 512, 0,
        ipWT, 512, nullptr, 0, 0,
        ip_b, nullptr,
        h_bf, nullptr, 0);

    for (int l = 0; l < 4; l++) {
        // [part1 | hm2T] = h @ [Wu1 | Wf]  (cols>=256 -> transposed per-batch store +bfv)
        gemm_tile<<<dim3(8, 128), 256, 0, stream>>>(
            256, 256,
            h_bf, 256, 0,
            updWT + l * 131072, 512,
            WfT + l * 65536, 256, 0,
            nullptr, bfv + l * 256,
            part1, hm2T, 0);
        // h = LN(invrs*(adjt@hm2) + part1 + upd_b + tbias + h) * g + b   (in-place)
        gemm_preln<<<512, 256, 0, stream>>>(
            adjt_bf, hm2T, invrs,
            upd_b + l * HH, tbias + l * BB * HH, part1,
            ln_g + l * HH, ln_b + l * HH, h_bf);
    }
    psum_kernel<<<dim3(32, 16), 256, 0, stream>>>(h_bf, partial);
    final_kernel<<<32, 256, 0, stream>>>(partial, op_W1, op_b1, sbuf);
    loss_kernel<<<511, 256, 0, stream>>>(sbuf, op_W2, op_b2, noise, out);
}